// Round 1
// baseline (284.373 us; speedup 1.0000x reference)
//
#include <hip/hip_runtime.h>
#include <hip/hip_bf16.h>

#define SEQ_LEN   20
#define USER_LEN  256
#define NTOK      (SEQ_LEN * USER_LEN)   // 5120
#define NC        64
#define CAND_N    1024
#define HID       128
#define TOPK      10
#define RHO_C     0.02f

// ---------------------------------------------------------------------------
// K1: candidate table. For each (centroid c, slot j): v = cand[c][j],
// vec_output[v] = relu(concat(vecs_use[v], temb[2]) @ W_ti1 + b_ti1) @ W_ti2 + b_ti2
// Stored component-major: tab[c][d][j] (d=0..19), tab[c][20][j] = |v|^2.
// ---------------------------------------------------------------------------
__global__ __launch_bounds__(256) void k_cand(
    const int* __restrict__ cand, const float* __restrict__ vecs,
    const float* __restrict__ temb,
    const float* __restrict__ W1, const float* __restrict__ b1,
    const float* __restrict__ W2, const float* __restrict__ b2,
    float* __restrict__ tab) {
  int g = blockIdx.x * 256 + threadIdx.x;     // [0, 65536)
  int v = cand[g];
  float in0[20];
  const float* vr = vecs + (size_t)v * 20;
  #pragma unroll
  for (int i = 0; i < 20; i++) in0[i] = vr[i];

  float h[40];
  #pragma unroll
  for (int j = 0; j < 40; j++) h[j] = b1[j];
  for (int i = 0; i < 20; i++) {
    float xi = in0[i];
    #pragma unroll
    for (int j = 0; j < 40; j++) h[j] = fmaf(xi, W1[i * 40 + j], h[j]);
  }
  for (int i = 0; i < 20; i++) {
    float xi = temb[40 + i];                  // time_embeddings[2]
    #pragma unroll
    for (int j = 0; j < 40; j++) h[j] = fmaf(xi, W1[(20 + i) * 40 + j], h[j]);
  }
  float o[20];
  #pragma unroll
  for (int k = 0; k < 20; k++) o[k] = b2[k];
  for (int i = 0; i < 40; i++) {
    float hv = fmaxf(h[i], 0.f);
    #pragma unroll
    for (int k = 0; k < 20; k++) o[k] = fmaf(hv, W2[i * 20 + k], o[k]);
  }
  int c = g >> 10, j = g & 1023;
  float* op = tab + (size_t)c * (21 * CAND_N) + j;
  float nrm = 0.f;
  #pragma unroll
  for (int k = 0; k < 20; k++) {
    op[k * CAND_N] = o[k];
    nrm = fmaf(o[k], o[k], nrm);
  }
  op[20 * CAND_N] = nrm;
}

// ---------------------------------------------------------------------------
// K2: per-token a = 0.5*(hist_mlp + timeout_mlp), plus |a|^2.
// hist input = concat(shift4, shift3, shift2, shift1, cur) of vecs_use[x].
// Weights are indexed by loop-uniform indices -> scalar (s_load) path.
// ---------------------------------------------------------------------------
__global__ __launch_bounds__(256) void k_token(
    const int* __restrict__ x, const int* __restrict__ t_slot,
    const float* __restrict__ vecs, const float* __restrict__ temb,
    const float* __restrict__ Ws1, const float* __restrict__ bs1,
    const float* __restrict__ Ws2, const float* __restrict__ bs2,
    const float* __restrict__ Wt1, const float* __restrict__ bt1,
    const float* __restrict__ Wt2, const float* __restrict__ bt2,
    float* __restrict__ aArr, float* __restrict__ aNorm) {
  int n = blockIdx.x * 256 + threadIdx.x;     // [0, 5120)
  int s = n >> 8;
  int u = n & 255;

  int xv = x[n];
  float e0[20];
  const float* e0p = vecs + (size_t)xv * 20;
  #pragma unroll
  for (int i = 0; i < 20; i++) e0[i] = e0p[i];

  // ---- time-transfer (outgoing) MLP ----
  int t = t_slot[n];
  int h24 = t % 24;
  int seg = (h24 >= 22 || h24 < 6) ? 0 : (h24 < 14 ? 1 : 2);
  const float* tp = temb + seg * 20;

  float h1[40];
  #pragma unroll
  for (int j = 0; j < 40; j++) h1[j] = bt1[j];
  for (int i = 0; i < 20; i++) {
    float xi = e0[i];
    #pragma unroll
    for (int j = 0; j < 40; j++) h1[j] = fmaf(xi, Wt1[i * 40 + j], h1[j]);
  }
  for (int i = 0; i < 20; i++) {
    float xi = tp[i];
    #pragma unroll
    for (int j = 0; j < 40; j++) h1[j] = fmaf(xi, Wt1[(20 + i) * 40 + j], h1[j]);
  }
  float xio[20];
  #pragma unroll
  for (int o = 0; o < 20; o++) xio[o] = bt2[o];
  for (int i = 0; i < 40; i++) {
    float hv = fmaxf(h1[i], 0.f);
    #pragma unroll
    for (int o = 0; o < 20; o++) xio[o] = fmaf(hv, Wt2[i * 20 + o], xio[o]);
  }

  // ---- 5-step history MLP (reuse h1) ----
  #pragma unroll
  for (int j = 0; j < 40; j++) h1[j] = bs1[j];
  for (int b = 0; b < 5; b++) {
    int sh = 4 - b;
    float tmp[20];
    if (b == 4) {
      #pragma unroll
      for (int i = 0; i < 20; i++) tmp[i] = e0[i];
    } else {
      int row = (s >= sh) ? (s - sh) : s;
      int xv2 = x[row * USER_LEN + u];
      const float* p = vecs + (size_t)xv2 * 20;
      #pragma unroll
      for (int i = 0; i < 20; i++) tmp[i] = p[i];
    }
    for (int i = 0; i < 20; i++) {
      float xi = tmp[i];
      #pragma unroll
      for (int j = 0; j < 40; j++) h1[j] = fmaf(xi, Ws1[(b * 20 + i) * 40 + j], h1[j]);
    }
  }
  float hout[20];
  #pragma unroll
  for (int o = 0; o < 20; o++) hout[o] = bs2[o];
  for (int i = 0; i < 40; i++) {
    float hv = fmaxf(h1[i], 0.f);
    #pragma unroll
    for (int o = 0; o < 20; o++) hout[o] = fmaf(hv, Ws2[i * 20 + o], hout[o]);
  }

  float nrm = 0.f;
  #pragma unroll
  for (int o = 0; o < 20; o++) {
    float av = 0.5f * (hout[o] + xio[o]);
    aArr[n * 20 + o] = av;
    nrm = fmaf(av, av, nrm);
  }
  aNorm[n] = nrm;
}

// ---------------------------------------------------------------------------
// K3: one block per token. d2 vs 1024 candidates (4/thread, coalesced over
// lanes), iterative wave top-10 extraction + merge, softmax-weighted
// 128-dim embedding combine. score=exp(-rho*dist) monotone in d2 -> select
// by smallest d2, only 10 sqrt/exp per token.
// ---------------------------------------------------------------------------
__global__ __launch_bounds__(256) void k_main(
    const int* __restrict__ x, const int* __restrict__ I_array,
    const int* __restrict__ cand, const float* __restrict__ tab,
    const float* __restrict__ aArr, const float* __restrict__ aNorm,
    const float* __restrict__ emb, float* __restrict__ out) {
  int n = blockIdx.x;
  int tid = threadIdx.x;
  int lane = tid & 63, w = tid >> 6;

  int xv = x[n];                 // uniform -> scalar loads
  int c = I_array[xv];
  float an = aNorm[n];
  float areg[20];
  const float* ap = aArr + n * 20;
  #pragma unroll
  for (int d = 0; d < 20; d++) areg[d] = ap[d];

  const float* T = tab + (size_t)c * (21 * CAND_N);
  float v0[4];
  int j0[4];
  #pragma unroll
  for (int r = 0; r < 4; r++) {
    int j = tid + 256 * r;
    float dot = 0.f;
    #pragma unroll
    for (int d = 0; d < 20; d++) dot = fmaf(areg[d], T[d * CAND_N + j], dot);
    v0[r] = an + T[20 * CAND_N + j] - 2.f * dot;
    j0[r] = j;
  }

  __shared__ float sPV[40];
  __shared__ int   sPJ[40];
  __shared__ float sVal[12];
  __shared__ int   sIdx[12];
  __shared__ float sE[12];
  __shared__ int   sIds[12];

  // per-wave top-10 by iterative extraction (butterfly argmin over 64 lanes)
  #pragma unroll 1
  for (int k = 0; k < TOPK; k++) {
    float bv = v0[0];
    int bj = j0[0];
    #pragma unroll
    for (int r = 1; r < 4; r++)
      if (v0[r] < bv || (v0[r] == bv && j0[r] < bj)) { bv = v0[r]; bj = j0[r]; }
    #pragma unroll
    for (int off = 1; off < 64; off <<= 1) {
      float ov = __shfl_xor(bv, off);
      int   oj = __shfl_xor(bj, off);
      if (ov < bv || (ov == bv && oj < bj)) { bv = ov; bj = oj; }
    }
    if (lane == 0) { sPV[w * TOPK + k] = bv; sPJ[w * TOPK + k] = bj; }
    #pragma unroll
    for (int r = 0; r < 4; r++)
      if (j0[r] == bj) v0[r] = 3.0e38f;
  }
  __syncthreads();

  // merge 4x10 partials (wave 0)
  if (w == 0) {
    float mv = 3.0e38f;
    int mj = 0x7fffffff;
    if (lane < 4 * TOPK) { mv = sPV[lane]; mj = sPJ[lane]; }
    #pragma unroll 1
    for (int k = 0; k < TOPK; k++) {
      float bv = mv;
      int bj = mj;
      #pragma unroll
      for (int off = 1; off < 64; off <<= 1) {
        float ov = __shfl_xor(bv, off);
        int   oj = __shfl_xor(bj, off);
        if (ov < bv || (ov == bv && oj < bj)) { bv = ov; bj = oj; }
      }
      if (lane == 0) { sVal[k] = bv; sIdx[k] = bj; }
      if (mj == bj) mv = 3.0e38f;   // j unique across entries
    }
  }
  __syncthreads();

  // scores + ids for the 10 winners + self
  if (tid < TOPK) {
    float dist = sqrtf(fmaxf(sVal[tid], 1e-12f));
    float sc = expf(-RHO_C * dist);
    sE[tid] = expf(sc);             // unnormalized softmax weight
    sIds[tid] = cand[c * CAND_N + sIdx[tid]];
  } else if (tid == TOPK) {
    sE[TOPK] = 2.7182818284590452f; // exp(1.0) for the self slot
    sIds[TOPK] = xv;
  }
  __syncthreads();

  if (tid < HID) {
    float denom = 0.f;
    #pragma unroll
    for (int k = 0; k < TOPK + 1; k++) denom += sE[k];
    float acc = 0.f;
    #pragma unroll
    for (int k = 0; k < TOPK + 1; k++)
      acc = fmaf(sE[k], emb[(size_t)sIds[k] * HID + tid], acc);
    out[(size_t)n * HID + tid] = acc / denom;
  }
}

// ---------------------------------------------------------------------------
extern "C" void kernel_launch(void* const* d_in, const int* in_sizes, int n_in,
                              void* d_out, int out_size, void* d_ws, size_t ws_size,
                              hipStream_t stream) {
  const int*   x      = (const int*)d_in[0];
  const int*   t_slot = (const int*)d_in[1];
  const float* vecs   = (const float*)d_in[2];
  const float* embn   = (const float*)d_in[3];
  const int*   I_arr  = (const int*)d_in[4];
  const int*   cand   = (const int*)d_in[5];
  const float* temb   = (const float*)d_in[6];
  const float* Ws1    = (const float*)d_in[7];
  const float* bs1    = (const float*)d_in[8];
  const float* Ws2    = (const float*)d_in[9];
  const float* bs2    = (const float*)d_in[10];
  const float* Wto1   = (const float*)d_in[11];
  const float* bto1   = (const float*)d_in[12];
  const float* Wto2   = (const float*)d_in[13];
  const float* bto2   = (const float*)d_in[14];
  const float* Wti1   = (const float*)d_in[15];
  const float* bti1   = (const float*)d_in[16];
  const float* Wti2   = (const float*)d_in[17];
  const float* bti2   = (const float*)d_in[18];

  float* tab   = (float*)d_ws;                      // 64*21*1024 floats (5.5 MB)
  float* aArr  = tab + NC * 21 * CAND_N;            // 5120*20
  float* aNorm = aArr + NTOK * 20;                  // 5120
  float* outp  = (float*)d_out;

  k_cand<<<(NC * CAND_N) / 256, 256, 0, stream>>>(cand, vecs, temb,
                                                  Wti1, bti1, Wti2, bti2, tab);
  k_token<<<NTOK / 256, 256, 0, stream>>>(x, t_slot, vecs, temb,
                                          Ws1, bs1, Ws2, bs2,
                                          Wto1, bto1, Wto2, bto2, aArr, aNorm);
  k_main<<<NTOK, 256, 0, stream>>>(x, I_arr, cand, tab, aArr, aNorm, embn, outp);
}

// Round 2
// 266.090 us; speedup vs baseline: 1.0687x; 1.0687x over previous
//
#include <hip/hip_runtime.h>
#include <hip/hip_bf16.h>

#define SEQ_LEN   20
#define USER_LEN  256
#define NTOK      (SEQ_LEN * USER_LEN)   // 5120
#define NC        64
#define CAND_N    1024
#define HID       128
#define TOPK      10
#define RHO_C     0.02f

// ---------------------------------------------------------------------------
// K1: candidate table. For each (centroid c, slot j): v = cand[c][j],
// vec_output[v] = relu(concat(vecs_use[v], temb[2]) @ W_ti1 + b_ti1) @ W_ti2 + b_ti2
// Stored component-major: tab[c][d][j] (d=0..19), tab[c][20][j] = |v|^2.
// ---------------------------------------------------------------------------
__global__ __launch_bounds__(256) void k_cand(
    const int* __restrict__ cand, const float* __restrict__ vecs,
    const float* __restrict__ temb,
    const float* __restrict__ W1, const float* __restrict__ b1,
    const float* __restrict__ W2, const float* __restrict__ b2,
    float* __restrict__ tab) {
  int g = blockIdx.x * 256 + threadIdx.x;     // [0, 65536)
  int v = cand[g];
  float in0[20];
  const float* vr = vecs + (size_t)v * 20;
  #pragma unroll
  for (int i = 0; i < 20; i++) in0[i] = vr[i];

  float h[40];
  #pragma unroll
  for (int j = 0; j < 40; j++) h[j] = b1[j];
  for (int i = 0; i < 20; i++) {
    float xi = in0[i];
    #pragma unroll
    for (int j = 0; j < 40; j++) h[j] = fmaf(xi, W1[i * 40 + j], h[j]);
  }
  for (int i = 0; i < 20; i++) {
    float xi = temb[40 + i];                  // time_embeddings[2]
    #pragma unroll
    for (int j = 0; j < 40; j++) h[j] = fmaf(xi, W1[(20 + i) * 40 + j], h[j]);
  }
  float o[20];
  #pragma unroll
  for (int k = 0; k < 20; k++) o[k] = b2[k];
  for (int i = 0; i < 40; i++) {
    float hv = fmaxf(h[i], 0.f);
    #pragma unroll
    for (int k = 0; k < 20; k++) o[k] = fmaf(hv, W2[i * 20 + k], o[k]);
  }
  int c = g >> 10, j = g & 1023;
  float* op = tab + (size_t)c * (21 * CAND_N) + j;
  float nrm = 0.f;
  #pragma unroll
  for (int k = 0; k < 20; k++) {
    op[k * CAND_N] = o[k];
    nrm = fmaf(o[k], o[k], nrm);
  }
  op[20 * CAND_N] = nrm;
}

// ---------------------------------------------------------------------------
// K2: per-token a = 0.5*(hist_mlp + timeout_mlp), plus |a|^2.
// ---------------------------------------------------------------------------
__global__ __launch_bounds__(256) void k_token(
    const int* __restrict__ x, const int* __restrict__ t_slot,
    const float* __restrict__ vecs, const float* __restrict__ temb,
    const float* __restrict__ Ws1, const float* __restrict__ bs1,
    const float* __restrict__ Ws2, const float* __restrict__ bs2,
    const float* __restrict__ Wt1, const float* __restrict__ bt1,
    const float* __restrict__ Wt2, const float* __restrict__ bt2,
    float* __restrict__ aArr, float* __restrict__ aNorm) {
  int n = blockIdx.x * 256 + threadIdx.x;     // [0, 5120)
  int s = n >> 8;
  int u = n & 255;

  int xv = x[n];
  float e0[20];
  const float* e0p = vecs + (size_t)xv * 20;
  #pragma unroll
  for (int i = 0; i < 20; i++) e0[i] = e0p[i];

  // ---- time-transfer (outgoing) MLP ----
  int t = t_slot[n];
  int h24 = t % 24;
  int seg = (h24 >= 22 || h24 < 6) ? 0 : (h24 < 14 ? 1 : 2);
  const float* tp = temb + seg * 20;

  float h1[40];
  #pragma unroll
  for (int j = 0; j < 40; j++) h1[j] = bt1[j];
  for (int i = 0; i < 20; i++) {
    float xi = e0[i];
    #pragma unroll
    for (int j = 0; j < 40; j++) h1[j] = fmaf(xi, Wt1[i * 40 + j], h1[j]);
  }
  for (int i = 0; i < 20; i++) {
    float xi = tp[i];
    #pragma unroll
    for (int j = 0; j < 40; j++) h1[j] = fmaf(xi, Wt1[(20 + i) * 40 + j], h1[j]);
  }
  float xio[20];
  #pragma unroll
  for (int o = 0; o < 20; o++) xio[o] = bt2[o];
  for (int i = 0; i < 40; i++) {
    float hv = fmaxf(h1[i], 0.f);
    #pragma unroll
    for (int o = 0; o < 20; o++) xio[o] = fmaf(hv, Wt2[i * 20 + o], xio[o]);
  }

  // ---- 5-step history MLP (reuse h1) ----
  #pragma unroll
  for (int j = 0; j < 40; j++) h1[j] = bs1[j];
  for (int b = 0; b < 5; b++) {
    int sh = 4 - b;
    float tmp[20];
    if (b == 4) {
      #pragma unroll
      for (int i = 0; i < 20; i++) tmp[i] = e0[i];
    } else {
      int row = (s >= sh) ? (s - sh) : s;
      int xv2 = x[row * USER_LEN + u];
      const float* p = vecs + (size_t)xv2 * 20;
      #pragma unroll
      for (int i = 0; i < 20; i++) tmp[i] = p[i];
    }
    for (int i = 0; i < 20; i++) {
      float xi = tmp[i];
      #pragma unroll
      for (int j = 0; j < 40; j++) h1[j] = fmaf(xi, Ws1[(b * 20 + i) * 40 + j], h1[j]);
    }
  }
  float hout[20];
  #pragma unroll
  for (int o = 0; o < 20; o++) hout[o] = bs2[o];
  for (int i = 0; i < 40; i++) {
    float hv = fmaxf(h1[i], 0.f);
    #pragma unroll
    for (int o = 0; o < 20; o++) hout[o] = fmaf(hv, Ws2[i * 20 + o], hout[o]);
  }

  float nrm = 0.f;
  #pragma unroll
  for (int o = 0; o < 20; o++) {
    float av = 0.5f * (hout[o] + xio[o]);
    aArr[n * 20 + o] = av;
    nrm = fmaf(av, av, nrm);
  }
  aNorm[n] = nrm;
}

// ---------------------------------------------------------------------------
// Bucketing: tokens grouped by centroid so k_dist reads each table slice ONCE.
// ---------------------------------------------------------------------------
__global__ __launch_bounds__(256) void kb_hist(
    const int* __restrict__ x, const int* __restrict__ I_array,
    int* __restrict__ cidx, int* __restrict__ cnt) {
  __shared__ int lc[NC];
  int tid = threadIdx.x;
  if (tid < NC) lc[tid] = 0;
  __syncthreads();
  int n = blockIdx.x * 256 + tid;
  int c = I_array[x[n]];
  cidx[n] = c;
  atomicAdd(&lc[c], 1);
  __syncthreads();
  if (tid < NC) atomicAdd(&cnt[tid], lc[tid]);
}

__global__ void kb_scan(const int* __restrict__ cnt, int* __restrict__ off,
                        int* __restrict__ cursor) {
  int lane = threadIdx.x;            // 0..63, single wave
  int v = cnt[lane];
  int inc = v;
  #pragma unroll
  for (int d = 1; d < 64; d <<= 1) {
    int t = __shfl_up(inc, d);
    if (lane >= d) inc += t;
  }
  off[lane + 1] = inc;
  if (lane == 0) off[0] = 0;
  cursor[lane] = inc - v;            // exclusive prefix
}

__global__ __launch_bounds__(256) void kb_scatter(
    const int* __restrict__ cidx, int* __restrict__ cursor,
    int* __restrict__ bucket) {
  int n = blockIdx.x * 256 + threadIdx.x;
  int c = cidx[n];
  int p = atomicAdd(&cursor[c], 1);
  bucket[p] = n;
}

// ---------------------------------------------------------------------------
// k_dist: grid = 64 centroids x 4 candidate-chunks. Candidate vector held in
// registers (table read exactly once); loop over this centroid's tokens with
// uniform (scalar) a-vector loads; write D2[n][j] coalesced.
// ---------------------------------------------------------------------------
__global__ __launch_bounds__(256) void k_dist(
    const float* __restrict__ tab, const float* __restrict__ aArr,
    const float* __restrict__ aNorm, const int* __restrict__ bucket,
    const int* __restrict__ off, float* __restrict__ D2) {
  int c = blockIdx.x >> 2;
  int j = ((blockIdx.x & 3) << 8) + threadIdx.x;
  const float* T = tab + (size_t)c * (21 * CAND_N);
  float cv[20];
  #pragma unroll
  for (int d = 0; d < 20; d++) cv[d] = T[d * CAND_N + j];
  float cn = T[20 * CAND_N + j];

  int begin = off[c], end = off[c + 1];
  #pragma unroll 2
  for (int it = begin; it < end; ++it) {
    int n = bucket[it];                   // uniform -> scalar load
    const float* ap = aArr + n * 20;      // uniform -> s_load path
    float dot = 0.f;
    #pragma unroll
    for (int d = 0; d < 20; d++) dot = fmaf(ap[d], cv[d], dot);
    D2[(size_t)n * CAND_N + j] = aNorm[n] + cn - 2.f * dot;
  }
}

// ---------------------------------------------------------------------------
// k_sel: ONE WAVE per token (all 5120 waves co-resident). 16 d2/lane via
// float4; 10 rounds of butterfly argmin (value-match invalidation, no indexed
// reg writes); fused softmax + 128-dim embedding combine.
// ---------------------------------------------------------------------------
__global__ __launch_bounds__(256) void k_sel(
    const float* __restrict__ D2, const int* __restrict__ cidx,
    const int* __restrict__ x, const int* __restrict__ cand,
    const float* __restrict__ emb, float* __restrict__ out) {
  int w = threadIdx.x >> 6, lane = threadIdx.x & 63;
  int n = blockIdx.x * 4 + w;
  int c = cidx[n];
  int xv = x[n];

  const float4* row = (const float4*)(D2 + (size_t)n * CAND_N);
  float v[16];
  #pragma unroll
  for (int k = 0; k < 4; k++) {
    float4 t = row[k * 64 + lane];        // j = k*256 + lane*4 + m
    v[k * 4 + 0] = t.x; v[k * 4 + 1] = t.y;
    v[k * 4 + 2] = t.z; v[k * 4 + 3] = t.w;
  }
  int lane4 = lane * 4;

  float acc0 = 0.f, acc1 = 0.f, esum = 0.f;
  #pragma unroll 1
  for (int r = 0; r < TOPK; r++) {
    // local argmin (j ascending with m; strict < keeps lowest j on ties)
    float bv = v[0];
    int bj = lane4;
    #pragma unroll
    for (int m = 1; m < 16; m++) {
      int jm = lane4 + ((m >> 2) * 256 + (m & 3));
      if (v[m] < bv) { bv = v[m]; bj = jm; }
    }
    // wave argmin butterfly (lexicographic (v, j))
    #pragma unroll
    for (int o = 1; o < 64; o <<= 1) {
      float ov = __shfl_xor(bv, o);
      int   oj = __shfl_xor(bj, o);
      if (ov < bv || (ov == bv && oj < bj)) { bv = ov; bj = oj; }
    }
    // weight + embedding gather (all lanes agree on bv,bj)
    float dist = sqrtf(fmaxf(bv, 1e-12f));
    float e = expf(expf(-RHO_C * dist));
    int id = cand[c * CAND_N + bj];
    esum += e;
    acc0 = fmaf(e, emb[(size_t)id * HID + lane], acc0);
    acc1 = fmaf(e, emb[(size_t)id * HID + 64 + lane], acc1);
    // invalidate winner (j unique across lanes/slots)
    #pragma unroll
    for (int m = 0; m < 16; m++) {
      int jm = lane4 + ((m >> 2) * 256 + (m & 3));
      if (jm == bj) v[m] = 3.0e38f;
    }
  }
  // self slot (value 1.0 -> weight exp(1))
  const float e1 = 2.71828182845904523536f;
  esum += e1;
  acc0 = fmaf(e1, emb[(size_t)xv * HID + lane], acc0);
  acc1 = fmaf(e1, emb[(size_t)xv * HID + 64 + lane], acc1);
  float inv = 1.0f / esum;
  out[(size_t)n * HID + lane] = acc0 * inv;
  out[(size_t)n * HID + 64 + lane] = acc1 * inv;
}

// ---------------------------------------------------------------------------
extern "C" void kernel_launch(void* const* d_in, const int* in_sizes, int n_in,
                              void* d_out, int out_size, void* d_ws, size_t ws_size,
                              hipStream_t stream) {
  const int*   x      = (const int*)d_in[0];
  const int*   t_slot = (const int*)d_in[1];
  const float* vecs   = (const float*)d_in[2];
  const float* embn   = (const float*)d_in[3];
  const int*   I_arr  = (const int*)d_in[4];
  const int*   cand   = (const int*)d_in[5];
  const float* temb   = (const float*)d_in[6];
  const float* Ws1    = (const float*)d_in[7];
  const float* bs1    = (const float*)d_in[8];
  const float* Ws2    = (const float*)d_in[9];
  const float* bs2    = (const float*)d_in[10];
  const float* Wto1   = (const float*)d_in[11];
  const float* bto1   = (const float*)d_in[12];
  const float* Wto2   = (const float*)d_in[13];
  const float* bto2   = (const float*)d_in[14];
  const float* Wti1   = (const float*)d_in[15];
  const float* bti1   = (const float*)d_in[16];
  const float* Wti2   = (const float*)d_in[17];
  const float* bti2   = (const float*)d_in[18];

  // workspace layout
  float* tab   = (float*)d_ws;                        // 64*21*1024
  float* aArr  = tab + NC * 21 * CAND_N;              // 5120*20
  float* aNorm = aArr + NTOK * 20;                    // 5120
  float* D2    = aNorm + NTOK;                        // 5120*1024 (21 MB)
  int*   cidx  = (int*)(D2 + (size_t)NTOK * CAND_N);  // 5120
  int*   cnt   = cidx + NTOK;                         // 64
  int*   off   = cnt + NC;                            // 65
  int*   cursor= off + NC + 1;                        // 64
  int*   bucket= cursor + NC;                         // 5120
  float* outp  = (float*)d_out;

  hipMemsetAsync(cnt, 0, NC * sizeof(int), stream);

  k_cand<<<(NC * CAND_N) / 256, 256, 0, stream>>>(cand, vecs, temb,
                                                  Wti1, bti1, Wti2, bti2, tab);
  k_token<<<NTOK / 256, 256, 0, stream>>>(x, t_slot, vecs, temb,
                                          Ws1, bs1, Ws2, bs2,
                                          Wto1, bto1, Wto2, bto2, aArr, aNorm);
  kb_hist<<<NTOK / 256, 256, 0, stream>>>(x, I_arr, cidx, cnt);
  kb_scan<<<1, 64, 0, stream>>>(cnt, off, cursor);
  kb_scatter<<<NTOK / 256, 256, 0, stream>>>(cidx, cursor, bucket);
  k_dist<<<NC * 4, 256, 0, stream>>>(tab, aArr, aNorm, bucket, off, D2);
  k_sel<<<NTOK / 4, 256, 0, stream>>>(D2, cidx, x, cand, embn, outp);
}

// Round 3
// 240.972 us; speedup vs baseline: 1.1801x; 1.1042x over previous
//
#include <hip/hip_runtime.h>
#include <hip/hip_bf16.h>

#define SEQ_LEN   20
#define USER_LEN  256
#define NTOK      (SEQ_LEN * USER_LEN)   // 5120
#define NC        64
#define CAND_N    1024
#define HID       128
#define TOPK      10
#define RHO_C     0.02f

// ---------------------------------------------------------------------------
// K1: candidate table, 8 threads per candidate, 32 candidates per block.
// tab[c][d][j] (d=0..19), tab[c][20][j] = |v|^2. Coalesced LDS->global store.
// ---------------------------------------------------------------------------
__global__ __launch_bounds__(256) void k_cand(
    const int* __restrict__ cand, const float* __restrict__ vecs,
    const float* __restrict__ temb,
    const float* __restrict__ W1, const float* __restrict__ b1,
    const float* __restrict__ W2, const float* __restrict__ b2,
    float* __restrict__ tab) {
  __shared__ float sIn[32][20];
  __shared__ float sHid[32][40];
  __shared__ float sOut[32][21];
  __shared__ float sT[20];
  int tid = threadIdx.x;
  int cc = tid >> 3, t = tid & 7;
  int g = blockIdx.x * 32 + cc;          // global (c,j) slot; blocks never straddle c
  int v = cand[g];
  if (tid < 20) sT[tid] = temb[40 + tid];          // time_embeddings[2]
  for (int i = t; i < 20; i += 8) sIn[cc][i] = vecs[(size_t)v * 20 + i];
  __syncthreads();

  #pragma unroll
  for (int q = 0; q < 5; q++) {
    int uu = t + 8 * q;                  // 0..39
    float acc = b1[uu];
    #pragma unroll
    for (int i = 0; i < 20; i++) acc = fmaf(sIn[cc][i], W1[i * 40 + uu], acc);
    #pragma unroll
    for (int i = 0; i < 20; i++) acc = fmaf(sT[i], W1[(20 + i) * 40 + uu], acc);
    sHid[cc][uu] = fmaxf(acc, 0.f);
  }
  __syncthreads();

  #pragma unroll
  for (int rr = 0; rr < 3; rr++) {
    int o = t + 8 * rr;
    if (o < 20) {
      float acc = b2[o];
      #pragma unroll
      for (int i = 0; i < 40; i++) acc = fmaf(sHid[cc][i], W2[i * 20 + o], acc);
      sOut[cc][o] = acc;
    }
  }
  __syncthreads();
  if (t == 0) {
    float nrm = 0.f;
    #pragma unroll
    for (int o = 0; o < 20; o++) nrm = fmaf(sOut[cc][o], sOut[cc][o], nrm);
    sOut[cc][20] = nrm;
  }
  __syncthreads();

  // coalesced store: 21 rows x 32 consecutive j per block
  int c = blockIdx.x >> 5;               // 32 blocks per centroid
  int jBase = (blockIdx.x & 31) * 32;
  float* base = tab + (size_t)c * (21 * CAND_N) + jBase;
  for (int idx = tid; idx < 21 * 32; idx += 256) {
    int o = idx >> 5, jj = idx & 31;
    base[o * CAND_N + jj] = sOut[jj][o];
  }
}

// ---------------------------------------------------------------------------
// K2: per-token a = 0.5*(hist_mlp + timeout_mlp) + |a|^2.
// 16 threads/token, 16 tokens/block, LDS-staged inputs & hidden.
// ---------------------------------------------------------------------------
__global__ __launch_bounds__(256) void k_token(
    const int* __restrict__ x, const int* __restrict__ t_slot,
    const float* __restrict__ vecs, const float* __restrict__ temb,
    const float* __restrict__ Ws1, const float* __restrict__ bs1,
    const float* __restrict__ Ws2, const float* __restrict__ bs2,
    const float* __restrict__ Wt1, const float* __restrict__ bt1,
    const float* __restrict__ Wt2, const float* __restrict__ bt2,
    float* __restrict__ aArr, float* __restrict__ aNorm) {
  __shared__ float sIn[16][140];   // [0..39] to-input (e0|temb_seg), [40..139] hist
  __shared__ float sHid[16][80];   // [0..39] to-hidden, [40..79] seq-hidden
  int tid = threadIdx.x;
  int tt = tid >> 4, t = tid & 15;
  int n = blockIdx.x * 16 + tt;
  int s = n >> 8, u = n & 255;
  int xv = x[n];
  int ts = t_slot[n];
  int h24 = ts % 24;
  int seg = (h24 >= 22 || h24 < 6) ? 0 : (h24 < 14 ? 1 : 2);

  // phase A: stage inputs (gathers issued 16-wide per token)
  for (int i = t; i < 140; i += 16) {
    float val;
    if (i < 20) val = vecs[(size_t)xv * 20 + i];
    else if (i < 40) val = temb[seg * 20 + (i - 20)];
    else {
      int ii = i - 40;
      int b = ii / 20, d = ii - b * 20;
      int sh = 4 - b;                              // b=4 -> cur
      int row = (s >= sh) ? s - sh : s;
      int xv2 = (sh == 0) ? xv : x[row * USER_LEN + u];
      val = vecs[(size_t)xv2 * 20 + d];
    }
    sIn[tt][i] = val;
  }
  __syncthreads();

  // phase B: 80 hidden units, 5 per thread
  #pragma unroll
  for (int q = 0; q < 5; q++) {
    int uu = t + 16 * q;               // 0..79
    float acc;
    if (uu < 40) {
      acc = bt1[uu];
      #pragma unroll
      for (int i = 0; i < 40; i++) acc = fmaf(sIn[tt][i], Wt1[i * 40 + uu], acc);
    } else {
      int u2 = uu - 40;
      acc = bs1[u2];
      #pragma unroll 4
      for (int i = 0; i < 100; i++) acc = fmaf(sIn[tt][40 + i], Ws1[i * 40 + u2], acc);
    }
    sHid[tt][uu] = fmaxf(acc, 0.f);
  }
  __syncthreads();

  // phase C: 20 outputs, fused a = 0.5*(xio + hout)
  #pragma unroll
  for (int rr = 0; rr < 2; rr++) {
    int o = t + 16 * rr;
    if (o < 20) {
      float acc = bt2[o] + bs2[o];
      #pragma unroll
      for (int i = 0; i < 40; i++) {
        acc = fmaf(sHid[tt][i],      Wt2[i * 20 + o], acc);
        acc = fmaf(sHid[tt][40 + i], Ws2[i * 20 + o], acc);
      }
      float av = 0.5f * acc;
      aArr[n * 20 + o] = av;
      sIn[tt][o] = av;                 // reuse for norm
    }
  }
  __syncthreads();
  if (t == 0) {
    float nrm = 0.f;
    #pragma unroll
    for (int o = 0; o < 20; o++) nrm = fmaf(sIn[tt][o], sIn[tt][o], nrm);
    aNorm[n] = nrm;
  }
}

// ---------------------------------------------------------------------------
// Bucketing fused into ONE single-block kernel: hist -> scan -> scatter.
// ---------------------------------------------------------------------------
__global__ __launch_bounds__(256) void kb_all(
    const int* __restrict__ x, const int* __restrict__ I_array,
    int* __restrict__ cidx, int* __restrict__ off, int* __restrict__ bucket) {
  __shared__ int lc[NC];
  __shared__ int lcur[NC];
  int tid = threadIdx.x;
  if (tid < NC) lc[tid] = 0;
  __syncthreads();
  for (int n = tid; n < NTOK; n += 256) {
    int c = I_array[x[n]];
    cidx[n] = c;
    atomicAdd(&lc[c], 1);
  }
  __syncthreads();
  if (tid < 64) {                       // wave 0
    int v = lc[tid];
    int inc = v;
    #pragma unroll
    for (int d = 1; d < 64; d <<= 1) {
      int tv = __shfl_up(inc, d);
      if (tid >= d) inc += tv;
    }
    off[tid + 1] = inc;
    if (tid == 0) off[0] = 0;
    lcur[tid] = inc - v;                // exclusive prefix
  }
  __syncthreads();
  for (int n = tid; n < NTOK; n += 256) {
    int p = atomicAdd(&lcur[cidx[n]], 1);
    bucket[p] = n;
  }
}

// ---------------------------------------------------------------------------
// k_dist: grid = 64 centroids x 4 candidate-chunks. Candidate vector in regs
// (table read exactly once); loop over centroid's tokens, write D2 coalesced.
// ---------------------------------------------------------------------------
__global__ __launch_bounds__(256) void k_dist(
    const float* __restrict__ tab, const float* __restrict__ aArr,
    const float* __restrict__ aNorm, const int* __restrict__ bucket,
    const int* __restrict__ off, float* __restrict__ D2) {
  int c = blockIdx.x >> 2;
  int j = ((blockIdx.x & 3) << 8) + threadIdx.x;
  const float* T = tab + (size_t)c * (21 * CAND_N);
  float cv[20];
  #pragma unroll
  for (int d = 0; d < 20; d++) cv[d] = T[d * CAND_N + j];
  float cn = T[20 * CAND_N + j];

  int begin = off[c], end = off[c + 1];
  #pragma unroll 2
  for (int it = begin; it < end; ++it) {
    int n = bucket[it];                   // uniform -> scalar load
    const float* ap = aArr + n * 20;      // uniform -> s_load path
    float dot = 0.f;
    #pragma unroll
    for (int d = 0; d < 20; d++) dot = fmaf(ap[d], cv[d], dot);
    D2[(size_t)n * CAND_N + j] = aNorm[n] + cn - 2.f * dot;
  }
}

// ---------------------------------------------------------------------------
// k_sel: one wave per token. 16 d2/lane via float4; 10 butterfly-argmin
// extractions; fused softmax + 128-dim embedding combine.
// ---------------------------------------------------------------------------
__global__ __launch_bounds__(256) void k_sel(
    const float* __restrict__ D2, const int* __restrict__ cidx,
    const int* __restrict__ x, const int* __restrict__ cand,
    const float* __restrict__ emb, float* __restrict__ out) {
  int w = threadIdx.x >> 6, lane = threadIdx.x & 63;
  int n = blockIdx.x * 4 + w;
  int c = cidx[n];
  int xv = x[n];

  const float4* row = (const float4*)(D2 + (size_t)n * CAND_N);
  float v[16];
  #pragma unroll
  for (int k = 0; k < 4; k++) {
    float4 t = row[k * 64 + lane];        // j = k*256 + lane*4 + m
    v[k * 4 + 0] = t.x; v[k * 4 + 1] = t.y;
    v[k * 4 + 2] = t.z; v[k * 4 + 3] = t.w;
  }
  int lane4 = lane * 4;

  float acc0 = 0.f, acc1 = 0.f, esum = 0.f;
  #pragma unroll 1
  for (int r = 0; r < TOPK; r++) {
    float bv = v[0];
    int bj = lane4;
    #pragma unroll
    for (int m = 1; m < 16; m++) {
      int jm = lane4 + ((m >> 2) * 256 + (m & 3));
      if (v[m] < bv) { bv = v[m]; bj = jm; }
    }
    #pragma unroll
    for (int o = 1; o < 64; o <<= 1) {
      float ov = __shfl_xor(bv, o);
      int   oj = __shfl_xor(bj, o);
      if (ov < bv || (ov == bv && oj < bj)) { bv = ov; bj = oj; }
    }
    float dist = sqrtf(fmaxf(bv, 1e-12f));
    float e = expf(expf(-RHO_C * dist));
    int id = cand[c * CAND_N + bj];
    esum += e;
    acc0 = fmaf(e, emb[(size_t)id * HID + lane], acc0);
    acc1 = fmaf(e, emb[(size_t)id * HID + 64 + lane], acc1);
    #pragma unroll
    for (int m = 0; m < 16; m++) {
      int jm = lane4 + ((m >> 2) * 256 + (m & 3));
      if (jm == bj) v[m] = 3.0e38f;
    }
  }
  const float e1 = 2.71828182845904523536f;   // exp(1.0) self slot
  esum += e1;
  acc0 = fmaf(e1, emb[(size_t)xv * HID + lane], acc0);
  acc1 = fmaf(e1, emb[(size_t)xv * HID + 64 + lane], acc1);
  float inv = 1.0f / esum;
  out[(size_t)n * HID + lane] = acc0 * inv;
  out[(size_t)n * HID + 64 + lane] = acc1 * inv;
}

// ---------------------------------------------------------------------------
extern "C" void kernel_launch(void* const* d_in, const int* in_sizes, int n_in,
                              void* d_out, int out_size, void* d_ws, size_t ws_size,
                              hipStream_t stream) {
  const int*   x      = (const int*)d_in[0];
  const int*   t_slot = (const int*)d_in[1];
  const float* vecs   = (const float*)d_in[2];
  const float* embn   = (const float*)d_in[3];
  const int*   I_arr  = (const int*)d_in[4];
  const int*   cand   = (const int*)d_in[5];
  const float* temb   = (const float*)d_in[6];
  const float* Ws1    = (const float*)d_in[7];
  const float* bs1    = (const float*)d_in[8];
  const float* Ws2    = (const float*)d_in[9];
  const float* bs2    = (const float*)d_in[10];
  const float* Wto1   = (const float*)d_in[11];
  const float* bto1   = (const float*)d_in[12];
  const float* Wto2   = (const float*)d_in[13];
  const float* bto2   = (const float*)d_in[14];
  const float* Wti1   = (const float*)d_in[15];
  const float* bti1   = (const float*)d_in[16];
  const float* Wti2   = (const float*)d_in[17];
  const float* bti2   = (const float*)d_in[18];

  // workspace layout
  float* tab   = (float*)d_ws;                        // 64*21*1024
  float* aArr  = tab + NC * 21 * CAND_N;              // 5120*20
  float* aNorm = aArr + NTOK * 20;                    // 5120
  float* D2    = aNorm + NTOK;                        // 5120*1024 (21 MB)
  int*   cidx  = (int*)(D2 + (size_t)NTOK * CAND_N);  // 5120
  int*   off   = cidx + NTOK;                         // 65
  int*   bucket= off + NC + 1;                        // 5120
  float* outp  = (float*)d_out;

  k_cand<<<(NC * CAND_N) / 32, 256, 0, stream>>>(cand, vecs, temb,
                                                 Wti1, bti1, Wti2, bti2, tab);
  k_token<<<NTOK / 16, 256, 0, stream>>>(x, t_slot, vecs, temb,
                                         Ws1, bs1, Ws2, bs2,
                                         Wto1, bto1, Wto2, bto2, aArr, aNorm);
  kb_all<<<1, 256, 0, stream>>>(x, I_arr, cidx, off, bucket);
  k_dist<<<NC * 4, 256, 0, stream>>>(tab, aArr, aNorm, bucket, off, D2);
  k_sel<<<NTOK / 4, 256, 0, stream>>>(D2, cidx, x, cand, embn, outp);
}

// Round 4
// 212.408 us; speedup vs baseline: 1.3388x; 1.1345x over previous
//
#include <hip/hip_runtime.h>
#include <hip/hip_bf16.h>

#define SEQ_LEN   20
#define USER_LEN  256
#define NTOK      (SEQ_LEN * USER_LEN)   // 5120
#define NC        64
#define CAND_N    1024
#define HID       128
#define TOPK      10
#define RHO_C     0.02f

#define CAND_BLKS (NC * CAND_N / 32)     // 2048
#define TOK_BLKS  (NTOK / 16)            // 320
#define MAXB      (NTOK / 8 + NC)        // 704 max (centroid,8-token) groups

// ---------------------------------------------------------------------------
// Kernel A: three independent roles fused into one launch.
//   blocks [0, 2048)      : candidate-table MLP -> tab[c][d][j], tab[c][20][j]=|v|^2
//   blocks [2048, 2368)   : per-token MLPs -> aArr, aNorm
//   block  2368           : bucketing (hist -> scan -> scatter -> block map)
// ---------------------------------------------------------------------------
__global__ __launch_bounds__(256) void k_pre(
    const int* __restrict__ x, const int* __restrict__ t_slot,
    const float* __restrict__ vecs, const float* __restrict__ temb,
    const int* __restrict__ I_array, const int* __restrict__ cand,
    const float* __restrict__ Ws1, const float* __restrict__ bs1,
    const float* __restrict__ Ws2, const float* __restrict__ bs2,
    const float* __restrict__ Wt1, const float* __restrict__ bt1,
    const float* __restrict__ Wt2, const float* __restrict__ bt2,
    const float* __restrict__ Wc1, const float* __restrict__ bc1,
    const float* __restrict__ Wc2, const float* __restrict__ bc2,
    float* __restrict__ tab, float* __restrict__ aArr, float* __restrict__ aNorm,
    int* __restrict__ bucket, int* __restrict__ blkInfo) {
  __shared__ union {
    struct { float sIn[32][20]; float sHid[32][40]; float sOut[32][21]; float sT[20]; } cd;
    struct { float sIn[16][140]; float sHid[16][80]; } tk;
    struct { int lc[NC]; int lcur[NC]; } kb;
  } U;
  int tid = threadIdx.x;

  if (blockIdx.x < CAND_BLKS) {
    // ---------------- candidate-table role ----------------
    int cc = tid >> 3, t = tid & 7;
    int g = blockIdx.x * 32 + cc;
    int v = cand[g];
    if (tid < 20) U.cd.sT[tid] = temb[40 + tid];       // time_embeddings[2]
    for (int i = t; i < 20; i += 8) U.cd.sIn[cc][i] = vecs[(size_t)v * 20 + i];
    __syncthreads();

    #pragma unroll
    for (int q = 0; q < 5; q++) {
      int uu = t + 8 * q;                  // 0..39
      float acc = bc1[uu];
      #pragma unroll
      for (int i = 0; i < 20; i++) acc = fmaf(U.cd.sIn[cc][i], Wc1[i * 40 + uu], acc);
      #pragma unroll
      for (int i = 0; i < 20; i++) acc = fmaf(U.cd.sT[i], Wc1[(20 + i) * 40 + uu], acc);
      U.cd.sHid[cc][uu] = fmaxf(acc, 0.f);
    }
    __syncthreads();

    #pragma unroll
    for (int rr = 0; rr < 3; rr++) {
      int o = t + 8 * rr;
      if (o < 20) {
        float acc = bc2[o];
        #pragma unroll
        for (int i = 0; i < 40; i++) acc = fmaf(U.cd.sHid[cc][i], Wc2[i * 20 + o], acc);
        U.cd.sOut[cc][o] = acc;
      }
    }
    __syncthreads();
    if (t == 0) {
      float nrm = 0.f;
      #pragma unroll
      for (int o = 0; o < 20; o++) nrm = fmaf(U.cd.sOut[cc][o], U.cd.sOut[cc][o], nrm);
      U.cd.sOut[cc][20] = nrm;
    }
    __syncthreads();

    int c = blockIdx.x >> 5;               // 32 blocks per centroid
    int jBase = (blockIdx.x & 31) * 32;
    float* base = tab + (size_t)c * (21 * CAND_N) + jBase;
    for (int idx = tid; idx < 21 * 32; idx += 256) {
      int o = idx >> 5, jj = idx & 31;
      base[o * CAND_N + jj] = U.cd.sOut[jj][o];
    }

  } else if (blockIdx.x < CAND_BLKS + TOK_BLKS) {
    // ---------------- token-MLP role ----------------
    int tt = tid >> 4, t = tid & 15;
    int n = (blockIdx.x - CAND_BLKS) * 16 + tt;
    int s = n >> 8, u = n & 255;
    int xv = x[n];
    int ts = t_slot[n];
    int h24 = ts % 24;
    int seg = (h24 >= 22 || h24 < 6) ? 0 : (h24 < 14 ? 1 : 2);

    for (int i = t; i < 140; i += 16) {
      float val;
      if (i < 20) val = vecs[(size_t)xv * 20 + i];
      else if (i < 40) val = temb[seg * 20 + (i - 20)];
      else {
        int ii = i - 40;
        int b = ii / 20, d = ii - b * 20;
        int sh = 4 - b;                              // b=4 -> current
        int row = (s >= sh) ? s - sh : s;
        int xv2 = (sh == 0) ? xv : x[row * USER_LEN + u];
        val = vecs[(size_t)xv2 * 20 + d];
      }
      U.tk.sIn[tt][i] = val;
    }
    __syncthreads();

    #pragma unroll
    for (int q = 0; q < 5; q++) {
      int uu = t + 16 * q;               // 0..79
      float acc;
      if (uu < 40) {
        acc = bt1[uu];
        #pragma unroll
        for (int i = 0; i < 40; i++) acc = fmaf(U.tk.sIn[tt][i], Wt1[i * 40 + uu], acc);
      } else {
        int u2 = uu - 40;
        acc = bs1[u2];
        #pragma unroll 4
        for (int i = 0; i < 100; i++) acc = fmaf(U.tk.sIn[tt][40 + i], Ws1[i * 40 + u2], acc);
      }
      U.tk.sHid[tt][uu] = fmaxf(acc, 0.f);
    }
    __syncthreads();

    #pragma unroll
    for (int rr = 0; rr < 2; rr++) {
      int o = t + 16 * rr;
      if (o < 20) {
        float acc = bt2[o] + bs2[o];
        #pragma unroll
        for (int i = 0; i < 40; i++) {
          acc = fmaf(U.tk.sHid[tt][i],      Wt2[i * 20 + o], acc);
          acc = fmaf(U.tk.sHid[tt][40 + i], Ws2[i * 20 + o], acc);
        }
        float av = 0.5f * acc;
        aArr[n * 20 + o] = av;
        U.tk.sIn[tt][o] = av;            // reuse for norm
      }
    }
    __syncthreads();
    if (t == 0) {
      float nrm = 0.f;
      #pragma unroll
      for (int o = 0; o < 20; o++) nrm = fmaf(U.tk.sIn[tt][o], U.tk.sIn[tt][o], nrm);
      aNorm[n] = nrm;
    }

  } else {
    // ---------------- bucketing role (single block) ----------------
    if (tid < NC) U.kb.lc[tid] = 0;
    for (int b = tid; b < MAXB; b += 256) blkInfo[b] = -1;
    __syncthreads();
    for (int n = tid; n < NTOK; n += 256)
      atomicAdd(&U.kb.lc[I_array[x[n]]], 1);
    __syncthreads();

    int v = 0, myStart = 0, nb = 0, blkStart = 0;
    if (tid < 64) {
      v = U.kb.lc[tid];
      int inc = v;
      #pragma unroll
      for (int d = 1; d < 64; d <<= 1) {
        int t2 = __shfl_up(inc, d);
        if (tid >= d) inc += t2;
      }
      myStart = inc - v;
      U.kb.lcur[tid] = myStart;
      nb = (v + 7) >> 3;
      int nbs = nb;
      #pragma unroll
      for (int d = 1; d < 64; d <<= 1) {
        int t2 = __shfl_up(nbs, d);
        if (tid >= d) nbs += t2;
      }
      blkStart = nbs - nb;
    }
    __syncthreads();
    for (int n = tid; n < NTOK; n += 256) {
      int c = I_array[x[n]];
      int p = atomicAdd(&U.kb.lcur[c], 1);
      bucket[p] = n;
    }
    if (tid < 64) {
      for (int k = 0; k < nb; k++) {
        int rem = v - 8 * k;
        int tc = rem < 8 ? rem : 8;
        blkInfo[blkStart + k] = (tid << 20) | (tc << 16) | (myStart + 8 * k);
      }
    }
  }
}

// ---------------------------------------------------------------------------
// Kernel B: fused distance + selection + output. One block per <=8 tokens of
// one centroid. Distances computed as an 8x20 x 20x1024 mini-matmul (table
// slice read once, float4 columns), kept in LDS; each wave then extracts
// top-10 for 2 tokens and writes the softmax-weighted embedding.
// ---------------------------------------------------------------------------
__global__ __launch_bounds__(256) void k_distsel(
    const int* __restrict__ blkInfo, const int* __restrict__ bucket,
    const float* __restrict__ tab, const float* __restrict__ aArr,
    const float* __restrict__ aNorm, const int* __restrict__ x,
    const int* __restrict__ cand, const float* __restrict__ emb,
    float* __restrict__ out) {
  int info = blkInfo[blockIdx.x];
  if (info < 0) return;
  int start = info & 0xFFFF;
  int tcnt  = (info >> 16) & 0xF;      // 1..8
  int c     = info >> 20;

  __shared__ float sA[8][20];
  __shared__ float sN[8];
  __shared__ int   sTok[8];
  __shared__ float sD[8][CAND_N];      // 32 KB

  int tid = threadIdx.x;
  if (tid < 8) {
    int live = tid < tcnt;
    int n = live ? bucket[start + tid] : 0;
    sTok[tid] = live ? n : -1;
    sN[tid] = live ? aNorm[n] : 0.f;
  }
  if (tid < 160) {
    int tt = tid / 20, d = tid - tt * 20;
    sA[tt][d] = (tt < tcnt) ? aArr[bucket[start + tt] * 20 + d] : 0.f;
  }
  __syncthreads();

  // ---- distance tile ----
  const float* T = tab + (size_t)c * (21 * CAND_N);
  int j4 = tid * 4;
  float4 acc[8];
  #pragma unroll
  for (int tt = 0; tt < 8; tt++) acc[tt] = make_float4(0.f, 0.f, 0.f, 0.f);
  #pragma unroll
  for (int dq = 0; dq < 5; dq++) {
    float4 t0 = *(const float4*)(T + (dq * 4 + 0) * CAND_N + j4);
    float4 t1 = *(const float4*)(T + (dq * 4 + 1) * CAND_N + j4);
    float4 t2 = *(const float4*)(T + (dq * 4 + 2) * CAND_N + j4);
    float4 t3 = *(const float4*)(T + (dq * 4 + 3) * CAND_N + j4);
    #pragma unroll
    for (int tt = 0; tt < 8; tt++) {
      float4 av = *(const float4*)(&sA[tt][dq * 4]);   // LDS broadcast
      acc[tt].x = fmaf(av.x, t0.x, acc[tt].x);
      acc[tt].y = fmaf(av.x, t0.y, acc[tt].y);
      acc[tt].z = fmaf(av.x, t0.z, acc[tt].z);
      acc[tt].w = fmaf(av.x, t0.w, acc[tt].w);
      acc[tt].x = fmaf(av.y, t1.x, acc[tt].x);
      acc[tt].y = fmaf(av.y, t1.y, acc[tt].y);
      acc[tt].z = fmaf(av.y, t1.z, acc[tt].z);
      acc[tt].w = fmaf(av.y, t1.w, acc[tt].w);
      acc[tt].x = fmaf(av.z, t2.x, acc[tt].x);
      acc[tt].y = fmaf(av.z, t2.y, acc[tt].y);
      acc[tt].z = fmaf(av.z, t2.z, acc[tt].z);
      acc[tt].w = fmaf(av.z, t2.w, acc[tt].w);
      acc[tt].x = fmaf(av.w, t3.x, acc[tt].x);
      acc[tt].y = fmaf(av.w, t3.y, acc[tt].y);
      acc[tt].z = fmaf(av.w, t3.z, acc[tt].z);
      acc[tt].w = fmaf(av.w, t3.w, acc[tt].w);
    }
  }
  float4 cn4 = *(const float4*)(T + 20 * CAND_N + j4);
  #pragma unroll
  for (int tt = 0; tt < 8; tt++) {
    float4 d2;
    d2.x = sN[tt] + cn4.x - 2.f * acc[tt].x;
    d2.y = sN[tt] + cn4.y - 2.f * acc[tt].y;
    d2.z = sN[tt] + cn4.z - 2.f * acc[tt].z;
    d2.w = sN[tt] + cn4.w - 2.f * acc[tt].w;
    *(float4*)(&sD[tt][j4]) = d2;
  }
  __syncthreads();

  // ---- selection: wave w handles tokens w and w+4 ----
  int lane = tid & 63, w = tid >> 6;
  #pragma unroll 1
  for (int pass = 0; pass < 2; pass++) {
    int tt = w + 4 * pass;
    if (tt >= tcnt) continue;
    int n = sTok[tt];
    int xv = x[n];

    float v[16];
    #pragma unroll
    for (int m = 0; m < 16; m++) v[m] = sD[tt][m * 64 + lane];  // j = m*64+lane

    float acc0 = 0.f, acc1 = 0.f, esum = 0.f;
    #pragma unroll 1
    for (int r = 0; r < TOPK; r++) {
      float bv = v[0];
      int bj = lane;
      #pragma unroll
      for (int m = 1; m < 16; m++) {
        int jm = (m << 6) | lane;
        if (v[m] < bv) { bv = v[m]; bj = jm; }     // m asc => j asc, < keeps low j
      }
      #pragma unroll
      for (int o = 1; o < 64; o <<= 1) {
        float ov = __shfl_xor(bv, o);
        int   oj = __shfl_xor(bj, o);
        if (ov < bv || (ov == bv && oj < bj)) { bv = ov; bj = oj; }
      }
      float dist = sqrtf(fmaxf(bv, 1e-12f));
      float e = expf(expf(-RHO_C * dist));
      int id = cand[c * CAND_N + bj];
      esum += e;
      acc0 = fmaf(e, emb[(size_t)id * HID + lane], acc0);
      acc1 = fmaf(e, emb[(size_t)id * HID + 64 + lane], acc1);
      #pragma unroll
      for (int m = 0; m < 16; m++) {
        int jm = (m << 6) | lane;
        if (jm == bj) v[m] = 3.0e38f;
      }
    }
    const float e1 = 2.71828182845904523536f;      // exp(1.0) self slot
    esum += e1;
    acc0 = fmaf(e1, emb[(size_t)xv * HID + lane], acc0);
    acc1 = fmaf(e1, emb[(size_t)xv * HID + 64 + lane], acc1);
    float inv = 1.0f / esum;
    out[(size_t)n * HID + lane] = acc0 * inv;
    out[(size_t)n * HID + 64 + lane] = acc1 * inv;
  }
}

// ---------------------------------------------------------------------------
extern "C" void kernel_launch(void* const* d_in, const int* in_sizes, int n_in,
                              void* d_out, int out_size, void* d_ws, size_t ws_size,
                              hipStream_t stream) {
  const int*   x      = (const int*)d_in[0];
  const int*   t_slot = (const int*)d_in[1];
  const float* vecs   = (const float*)d_in[2];
  const float* embn   = (const float*)d_in[3];
  const int*   I_arr  = (const int*)d_in[4];
  const int*   cand   = (const int*)d_in[5];
  const float* temb   = (const float*)d_in[6];
  const float* Ws1    = (const float*)d_in[7];
  const float* bs1    = (const float*)d_in[8];
  const float* Ws2    = (const float*)d_in[9];
  const float* bs2    = (const float*)d_in[10];
  const float* Wto1   = (const float*)d_in[11];
  const float* bto1   = (const float*)d_in[12];
  const float* Wto2   = (const float*)d_in[13];
  const float* bto2   = (const float*)d_in[14];
  const float* Wti1   = (const float*)d_in[15];
  const float* bti1   = (const float*)d_in[16];
  const float* Wti2   = (const float*)d_in[17];
  const float* bti2   = (const float*)d_in[18];

  // workspace layout (~5.9 MB)
  float* tab    = (float*)d_ws;                       // 64*21*1024
  float* aArr   = tab + NC * 21 * CAND_N;             // 5120*20
  float* aNorm  = aArr + NTOK * 20;                   // 5120
  int*   bucket = (int*)(aNorm + NTOK);               // 5120
  int*   blkInfo= bucket + NTOK;                      // 704
  float* outp   = (float*)d_out;

  k_pre<<<CAND_BLKS + TOK_BLKS + 1, 256, 0, stream>>>(
      x, t_slot, vecs, temb, I_arr, cand,
      Ws1, bs1, Ws2, bs2, Wto1, bto1, Wto2, bto2,
      Wti1, bti1, Wti2, bti2,
      tab, aArr, aNorm, bucket, blkInfo);
  k_distsel<<<MAXB, 256, 0, stream>>>(blkInfo, bucket, tab, aArr, aNorm,
                                      x, cand, embn, outp);
}

// Round 5
// 193.780 us; speedup vs baseline: 1.4675x; 1.0961x over previous
//
#include <hip/hip_runtime.h>
#include <hip/hip_bf16.h>

#define SEQ_LEN   20
#define USER_LEN  256
#define NTOK      (SEQ_LEN * USER_LEN)   // 5120
#define NC        64
#define CAND_N    1024
#define HID       128
#define TOPK      10
#define RHO_C     0.02f

#define CAND_BLKS 256                    // 65536 threads, 1/candidate
#define TO_BLKS   (NTOK / 256)           // 20
#define SEQ_BLKS  (NTOK / 256)           // 20
#define MAXB      (NTOK / 8 + NC)        // 704 max (centroid,8-token) groups

// ---------------------------------------------------------------------------
// Kernel A: four roles, all thread-per-item, streamed inputs, scalar weights,
// no LDS (except the single bucketing block).
//   [0,256)    : candidate-table MLP -> tab[c][d][j], tab[c][20][j]=|v|^2
//   [256,276)  : per-token "to" MLP  -> aX[n][20]
//   [276,296)  : per-token "seq" MLP -> aH[n][20]
//   296        : bucketing (hist -> scan -> scatter -> block map)
// ---------------------------------------------------------------------------
__global__ __launch_bounds__(256, 2) void k_pre(
    const int* __restrict__ x, const int* __restrict__ t_slot,
    const float* __restrict__ vecs, const float* __restrict__ temb,
    const int* __restrict__ I_array, const int* __restrict__ cand,
    const float* __restrict__ Ws1, const float* __restrict__ bs1,
    const float* __restrict__ Ws2, const float* __restrict__ bs2,
    const float* __restrict__ Wt1, const float* __restrict__ bt1,
    const float* __restrict__ Wt2, const float* __restrict__ bt2,
    const float* __restrict__ Wc1, const float* __restrict__ bc1,
    const float* __restrict__ Wc2, const float* __restrict__ bc2,
    float* __restrict__ tab, float* __restrict__ aX, float* __restrict__ aH,
    int* __restrict__ bucket, int* __restrict__ blkInfo) {
  int tid = threadIdx.x;

  if (blockIdx.x < CAND_BLKS) {
    // ---------------- candidate-table role: 1 thread / candidate ----------
    int g = blockIdx.x * 256 + tid;            // (c,j) slot
    int v = cand[g];
    float h[40];
    #pragma unroll
    for (int j = 0; j < 40; j++) h[j] = bc1[j];
    // time part (uniform): temb[2] contribution
    #pragma unroll
    for (int q = 0; q < 5; q++) {
      float4 t4 = *(const float4*)(temb + 40 + 4 * q);
      #pragma unroll
      for (int r = 0; r < 4; r++) {
        float ti = (&t4.x)[r];
        #pragma unroll
        for (int j = 0; j < 40; j++) h[j] = fmaf(ti, Wc1[(20 + 4 * q + r) * 40 + j], h[j]);
      }
    }
    // location part, streamed float4
    const float4* vp = (const float4*)(vecs + (size_t)v * 20);
    #pragma unroll
    for (int q = 0; q < 5; q++) {
      float4 e = vp[q];
      #pragma unroll
      for (int r = 0; r < 4; r++) {
        float xi = (&e.x)[r];
        #pragma unroll
        for (int j = 0; j < 40; j++) h[j] = fmaf(xi, Wc1[(4 * q + r) * 40 + j], h[j]);
      }
    }
    float o[20];
    #pragma unroll
    for (int k = 0; k < 20; k++) o[k] = bc2[k];
    #pragma unroll 8
    for (int i = 0; i < 40; i++) {
      float hv = fmaxf(h[i], 0.f);
      #pragma unroll
      for (int k = 0; k < 20; k++) o[k] = fmaf(hv, Wc2[i * 20 + k], o[k]);
    }
    int c = g >> 10, j = g & 1023;
    float* op = tab + (size_t)c * (21 * CAND_N) + j;
    float nrm = 0.f;
    #pragma unroll
    for (int k = 0; k < 20; k++) {
      op[k * CAND_N] = o[k];
      nrm = fmaf(o[k], o[k], nrm);
    }
    op[20 * CAND_N] = nrm;

  } else if (blockIdx.x < CAND_BLKS + TO_BLKS) {
    // ---------------- "to" MLP role: 1 thread / token ----------------------
    int n = (blockIdx.x - CAND_BLKS) * 256 + tid;
    int xv = x[n];
    int ts = t_slot[n];
    int h24 = ts % 24;
    int seg = (h24 >= 22 || h24 < 6) ? 0 : (h24 < 14 ? 1 : 2);
    float h[40];
    #pragma unroll
    for (int j = 0; j < 40; j++) h[j] = bt1[j];
    const float4* ep = (const float4*)(vecs + (size_t)xv * 20);
    #pragma unroll
    for (int q = 0; q < 5; q++) {
      float4 e = ep[q];
      #pragma unroll
      for (int r = 0; r < 4; r++) {
        float xi = (&e.x)[r];
        #pragma unroll
        for (int j = 0; j < 40; j++) h[j] = fmaf(xi, Wt1[(4 * q + r) * 40 + j], h[j]);
      }
    }
    const float4* tp = (const float4*)(temb + seg * 20);   // 80B-aligned
    #pragma unroll
    for (int q = 0; q < 5; q++) {
      float4 e = tp[q];
      #pragma unroll
      for (int r = 0; r < 4; r++) {
        float xi = (&e.x)[r];
        #pragma unroll
        for (int j = 0; j < 40; j++) h[j] = fmaf(xi, Wt1[(20 + 4 * q + r) * 40 + j], h[j]);
      }
    }
    float o[20];
    #pragma unroll
    for (int k = 0; k < 20; k++) o[k] = bt2[k];
    #pragma unroll 8
    for (int i = 0; i < 40; i++) {
      float hv = fmaxf(h[i], 0.f);
      #pragma unroll
      for (int k = 0; k < 20; k++) o[k] = fmaf(hv, Wt2[i * 20 + k], o[k]);
    }
    #pragma unroll
    for (int k = 0; k < 20; k++) aX[n * 20 + k] = o[k];

  } else if (blockIdx.x < CAND_BLKS + TO_BLKS + SEQ_BLKS) {
    // ---------------- "seq" MLP role: 1 thread / token ---------------------
    int n = (blockIdx.x - CAND_BLKS - TO_BLKS) * 256 + tid;
    int s = n >> 8, u = n & 255;
    float h[40];
    #pragma unroll
    for (int j = 0; j < 40; j++) h[j] = bs1[j];
    #pragma unroll 1
    for (int b = 0; b < 5; b++) {
      int sh = 4 - b;                        // b=4 -> sh=0 -> current token
      int row = (s >= sh) ? s - sh : s;
      int xv2 = x[row * USER_LEN + u];
      const float4* p = (const float4*)(vecs + (size_t)xv2 * 20);
      #pragma unroll
      for (int q = 0; q < 5; q++) {
        float4 e = p[q];
        #pragma unroll
        for (int r = 0; r < 4; r++) {
          float xi = (&e.x)[r];
          #pragma unroll
          for (int j = 0; j < 40; j++) h[j] = fmaf(xi, Ws1[(b * 20 + 4 * q + r) * 40 + j], h[j]);
        }
      }
    }
    float o[20];
    #pragma unroll
    for (int k = 0; k < 20; k++) o[k] = bs2[k];
    #pragma unroll 8
    for (int i = 0; i < 40; i++) {
      float hv = fmaxf(h[i], 0.f);
      #pragma unroll
      for (int k = 0; k < 20; k++) o[k] = fmaf(hv, Ws2[i * 20 + k], o[k]);
    }
    #pragma unroll
    for (int k = 0; k < 20; k++) aH[n * 20 + k] = o[k];

  } else {
    // ---------------- bucketing role (single block) ------------------------
    __shared__ int lc[NC];
    __shared__ int lcur[NC];
    if (tid < NC) lc[tid] = 0;
    for (int b = tid; b < MAXB; b += 256) blkInfo[b] = -1;
    __syncthreads();
    for (int n = tid; n < NTOK; n += 256)
      atomicAdd(&lc[I_array[x[n]]], 1);
    __syncthreads();

    int v = 0, myStart = 0, nb = 0, blkStart = 0;
    if (tid < 64) {
      v = lc[tid];
      int inc = v;
      #pragma unroll
      for (int d = 1; d < 64; d <<= 1) {
        int t2 = __shfl_up(inc, d);
        if (tid >= d) inc += t2;
      }
      myStart = inc - v;
      lcur[tid] = myStart;
      nb = (v + 7) >> 3;
      int nbs = nb;
      #pragma unroll
      for (int d = 1; d < 64; d <<= 1) {
        int t2 = __shfl_up(nbs, d);
        if (tid >= d) nbs += t2;
      }
      blkStart = nbs - nb;
    }
    __syncthreads();
    for (int n = tid; n < NTOK; n += 256) {
      int c = I_array[x[n]];
      int p = atomicAdd(&lcur[c], 1);
      bucket[p] = n;
    }
    if (tid < 64) {
      for (int k = 0; k < nb; k++) {
        int rem = v - 8 * k;
        int tc = rem < 8 ? rem : 8;
        blkInfo[blkStart + k] = (tid << 20) | (tc << 16) | (myStart + 8 * k);
      }
    }
  }
}

// ---------------------------------------------------------------------------
// Kernel B: fused distance + selection + output. One block per <=8 tokens of
// one centroid. a = 0.5*(aH+aX) and |a|^2 computed during staging.
// ---------------------------------------------------------------------------
__global__ __launch_bounds__(256) void k_distsel(
    const int* __restrict__ blkInfo, const int* __restrict__ bucket,
    const float* __restrict__ tab, const float* __restrict__ aX,
    const float* __restrict__ aH, const int* __restrict__ x,
    const int* __restrict__ cand, const float* __restrict__ emb,
    float* __restrict__ out) {
  int info = blkInfo[blockIdx.x];
  if (info < 0) return;
  int start = info & 0xFFFF;
  int tcnt  = (info >> 16) & 0xF;      // 1..8
  int c     = info >> 20;

  __shared__ float sA[8][20];
  __shared__ float sN[8];
  __shared__ int   sTok[8];
  __shared__ float sD[8][CAND_N];      // 32 KB

  int tid = threadIdx.x;
  if (tid < 8) sTok[tid] = (tid < tcnt) ? bucket[start + tid] : -1;
  if (tid < 160) {
    int tt = tid / 20, d = tid - tt * 20;
    if (tt < tcnt) {
      int n = bucket[start + tt];
      sA[tt][d] = 0.5f * (aH[n * 20 + d] + aX[n * 20 + d]);
    } else {
      sA[tt][d] = 0.f;
    }
  }
  __syncthreads();
  if (tid < 8) {
    float nrm = 0.f;
    #pragma unroll
    for (int d = 0; d < 20; d++) nrm = fmaf(sA[tid][d], sA[tid][d], nrm);
    sN[tid] = nrm;
  }
  __syncthreads();

  // ---- distance tile: 8x20 @ 20x1024 ----
  const float* T = tab + (size_t)c * (21 * CAND_N);
  int j4 = tid * 4;
  float4 acc[8];
  #pragma unroll
  for (int tt = 0; tt < 8; tt++) acc[tt] = make_float4(0.f, 0.f, 0.f, 0.f);
  #pragma unroll
  for (int dq = 0; dq < 5; dq++) {
    float4 t0 = *(const float4*)(T + (dq * 4 + 0) * CAND_N + j4);
    float4 t1 = *(const float4*)(T + (dq * 4 + 1) * CAND_N + j4);
    float4 t2 = *(const float4*)(T + (dq * 4 + 2) * CAND_N + j4);
    float4 t3 = *(const float4*)(T + (dq * 4 + 3) * CAND_N + j4);
    #pragma unroll
    for (int tt = 0; tt < 8; tt++) {
      float4 av = *(const float4*)(&sA[tt][dq * 4]);   // LDS broadcast
      acc[tt].x = fmaf(av.x, t0.x, acc[tt].x);
      acc[tt].y = fmaf(av.x, t0.y, acc[tt].y);
      acc[tt].z = fmaf(av.x, t0.z, acc[tt].z);
      acc[tt].w = fmaf(av.x, t0.w, acc[tt].w);
      acc[tt].x = fmaf(av.y, t1.x, acc[tt].x);
      acc[tt].y = fmaf(av.y, t1.y, acc[tt].y);
      acc[tt].z = fmaf(av.y, t1.z, acc[tt].z);
      acc[tt].w = fmaf(av.y, t1.w, acc[tt].w);
      acc[tt].x = fmaf(av.z, t2.x, acc[tt].x);
      acc[tt].y = fmaf(av.z, t2.y, acc[tt].y);
      acc[tt].z = fmaf(av.z, t2.z, acc[tt].z);
      acc[tt].w = fmaf(av.z, t2.w, acc[tt].w);
      acc[tt].x = fmaf(av.w, t3.x, acc[tt].x);
      acc[tt].y = fmaf(av.w, t3.y, acc[tt].y);
      acc[tt].z = fmaf(av.w, t3.z, acc[tt].z);
      acc[tt].w = fmaf(av.w, t3.w, acc[tt].w);
    }
  }
  float4 cn4 = *(const float4*)(T + 20 * CAND_N + j4);
  #pragma unroll
  for (int tt = 0; tt < 8; tt++) {
    float4 d2;
    d2.x = sN[tt] + cn4.x - 2.f * acc[tt].x;
    d2.y = sN[tt] + cn4.y - 2.f * acc[tt].y;
    d2.z = sN[tt] + cn4.z - 2.f * acc[tt].z;
    d2.w = sN[tt] + cn4.w - 2.f * acc[tt].w;
    *(float4*)(&sD[tt][j4]) = d2;
  }
  __syncthreads();

  // ---- selection: wave w handles tokens w and w+4 ----
  int lane = tid & 63, w = tid >> 6;
  #pragma unroll 1
  for (int pass = 0; pass < 2; pass++) {
    int tt = w + 4 * pass;
    if (tt >= tcnt) continue;
    int n = sTok[tt];
    int xv = x[n];

    float v[16];
    #pragma unroll
    for (int m = 0; m < 16; m++) v[m] = sD[tt][m * 64 + lane];  // j = m*64+lane

    float acc0 = 0.f, acc1 = 0.f, esum = 0.f;
    #pragma unroll 1
    for (int r = 0; r < TOPK; r++) {
      float bv = v[0];
      int bj = lane;
      #pragma unroll
      for (int m = 1; m < 16; m++) {
        int jm = (m << 6) | lane;
        if (v[m] < bv) { bv = v[m]; bj = jm; }     // m asc => j asc, < keeps low j
      }
      #pragma unroll
      for (int o = 1; o < 64; o <<= 1) {
        float ov = __shfl_xor(bv, o);
        int   oj = __shfl_xor(bj, o);
        if (ov < bv || (ov == bv && oj < bj)) { bv = ov; bj = oj; }
      }
      float dist = sqrtf(fmaxf(bv, 1e-12f));
      float e = expf(expf(-RHO_C * dist));
      int id = cand[c * CAND_N + bj];
      esum += e;
      acc0 = fmaf(e, emb[(size_t)id * HID + lane], acc0);
      acc1 = fmaf(e, emb[(size_t)id * HID + 64 + lane], acc1);
      #pragma unroll
      for (int m = 0; m < 16; m++) {
        int jm = (m << 6) | lane;
        if (jm == bj) v[m] = 3.0e38f;
      }
    }
    const float e1 = 2.71828182845904523536f;      // exp(1.0) self slot
    esum += e1;
    acc0 = fmaf(e1, emb[(size_t)xv * HID + lane], acc0);
    acc1 = fmaf(e1, emb[(size_t)xv * HID + 64 + lane], acc1);
    float inv = 1.0f / esum;
    out[(size_t)n * HID + lane] = acc0 * inv;
    out[(size_t)n * HID + 64 + lane] = acc1 * inv;
  }
}

// ---------------------------------------------------------------------------
extern "C" void kernel_launch(void* const* d_in, const int* in_sizes, int n_in,
                              void* d_out, int out_size, void* d_ws, size_t ws_size,
                              hipStream_t stream) {
  const int*   x      = (const int*)d_in[0];
  const int*   t_slot = (const int*)d_in[1];
  const float* vecs   = (const float*)d_in[2];
  const float* embn   = (const float*)d_in[3];
  const int*   I_arr  = (const int*)d_in[4];
  const int*   cand   = (const int*)d_in[5];
  const float* temb   = (const float*)d_in[6];
  const float* Ws1    = (const float*)d_in[7];
  const float* bs1    = (const float*)d_in[8];
  const float* Ws2    = (const float*)d_in[9];
  const float* bs2    = (const float*)d_in[10];
  const float* Wto1   = (const float*)d_in[11];
  const float* bto1   = (const float*)d_in[12];
  const float* Wto2   = (const float*)d_in[13];
  const float* bto2   = (const float*)d_in[14];
  const float* Wti1   = (const float*)d_in[15];
  const float* bti1   = (const float*)d_in[16];
  const float* Wti2   = (const float*)d_in[17];
  const float* bti2   = (const float*)d_in[18];

  // workspace layout (~6.3 MB)
  float* tab    = (float*)d_ws;                       // 64*21*1024
  float* aX     = tab + NC * 21 * CAND_N;             // 5120*20
  float* aH     = aX + NTOK * 20;                     // 5120*20
  int*   bucket = (int*)(aH + NTOK * 20);             // 5120
  int*   blkInfo= bucket + NTOK;                      // 704
  float* outp   = (float*)d_out;

  k_pre<<<CAND_BLKS + TO_BLKS + SEQ_BLKS + 1, 256, 0, stream>>>(
      x, t_slot, vecs, temb, I_arr, cand,
      Ws1, bs1, Ws2, bs2, Wto1, bto1, Wto2, bto2,
      Wti1, bti1, Wti2, bti2,
      tab, aX, aH, bucket, blkInfo);
  k_distsel<<<MAXB, 256, 0, stream>>>(blkInfo, bucket, tab, aX, aH,
                                      x, cand, embn, outp);
}